// Round 3
// baseline (278.527 us; speedup 1.0000x reference)
//
#include <hip/hip_runtime.h>

// RIDE 4-way self-distillation KL loss, N x C (C=7), fp32. Scalar output.
//
// R2 post-mortem: L3-resident replay dispatches (hbm_bytes=16KB) ran the same
// 91 us as HBM-heavy ones -> on-chip bound, not HBM-bound. global_load_lds
// prefetch is defeated by compiler-inserted vmcnt(0) before ds_read (LDS-DMA
// alias conservatism) -> burst/drain every iteration. R1's plain loads had
// lane-stride 112 B -> ~112 cache lines per wave instruction -> TCP-serial.
//
// This version: lane-CONTIGUOUS global loads into VGPRs (16 lines/instr),
// wave-private LDS transpose via ordinary ds_write/ds_read (lgkmcnt-tracked,
// no false alias with in-flight global loads), ZERO barriers. Per wave:
// stage = 256 rows x 4 arrays = 28 KB in 112 VGPRs; pipeline: ds_write stage
// s -> issue loads s+1 -> compute s from LDS. 28 KB/wave stays in flight
// through compute; 4 waves/CU ~ 112 KB outstanding, never drained by a sync.

struct RideConsts {
    float invT[7];
    float scale;   // mean(T^2) / (3*N)
};

__global__ __launch_bounds__(64, 1) void ride_kernel(
    const float* __restrict__ x1, const float* __restrict__ x2,
    const float* __restrict__ x3, const float* __restrict__ x4,
    float* __restrict__ out, RideConsts cst, int stages)
{
    // One wave per block: whole LDS is wave-private. 4 arrays x 1792 floats
    // (256 rows x 7) = 28672 B.
    __shared__ __align__(16) float lds[4][1792];

    const int L = threadIdx.x;           // lane 0..63
    const float* xs[4] = {x1, x2, x3, x4};

    // This wave owns rows [blockIdx.x*256*stages, +256*stages).
    // Per array, stage s starts at float4 index b4base + s*448 (448 f4/stage).
    const long long b4base = (long long)blockIdx.x * stages * 448;

    float4 v[28];   // staged chunk: [array][piece] contiguous 1 KB pieces

    // Prologue: load stage 0.
#pragma unroll
    for (int a = 0; a < 4; ++a) {
        const float4* p = (const float4*)xs[a] + b4base + L;
#pragma unroll
        for (int k = 0; k < 7; ++k) v[a * 7 + k] = p[k * 64];
    }

    float cost_sum = 0.0f;

    for (int s = 0; s < stages; ++s) {
        // 1) Commit stage s to private LDS (vmcnt waits happen here, ~a full
        //    compute-phase after these loads were issued).
#pragma unroll
        for (int a = 0; a < 4; ++a) {
            float4* dst = (float4*)&lds[a][0];
#pragma unroll
            for (int k = 0; k < 7; ++k) dst[k * 64 + L] = v[a * 7 + k];
        }

        // 2) Issue stage s+1 loads; they stay in flight during compute below.
        if (s + 1 < stages) {
            const long long nb4 = b4base + (long long)(s + 1) * 448 + L;
#pragma unroll
            for (int a = 0; a < 4; ++a) {
                const float4* p = (const float4*)xs[a] + nb4;
#pragma unroll
                for (int k = 0; k < 7; ++k) v[a * 7 + k] = p[k * 64];
            }
        }

        // 3) Compute stage s: lane L owns rows 4L..4L+3. Row data at float4
        //    indices 7L+k -> byte 112L+16k: 2-lanes/bank, conflict-free.
        float q4[28], qlogq[4];
        {   // teacher (array 0)
            float f[28];
            const float4* base = (const float4*)&lds[0][0];
#pragma unroll
            for (int k = 0; k < 7; ++k) {
                float4 t = base[7 * L + k];
                f[4*k] = t.x; f[4*k+1] = t.y; f[4*k+2] = t.z; f[4*k+3] = t.w;
            }
#pragma unroll
            for (int rr = 0; rr < 4; ++rr) {
                float z[7], m = -1e30f;
#pragma unroll
                for (int c = 0; c < 7; ++c) {
                    z[c] = f[7*rr+c] * cst.invT[c];
                    m = fmaxf(m, z[c]);
                }
                float S = 0.0f;
#pragma unroll
                for (int c = 0; c < 7; ++c) {
                    float e = __expf(z[c] - m);
                    q4[7*rr+c] = e; S += e;
                }
                const float invS = 1.0f / S, logS = __logf(S);
                float sq = 0.0f;
#pragma unroll
                for (int c = 0; c < 7; ++c) {
                    float qq = q4[7*rr+c] * invS;
                    q4[7*rr+c] = qq;
                    sq += qq * (z[c] - m - logS);
                }
                qlogq[rr] = sq;
            }
        }
#pragma unroll
        for (int a = 1; a < 4; ++a) {   // students
            float g[28];
            const float4* base = (const float4*)&lds[a][0];
#pragma unroll
            for (int k = 0; k < 7; ++k) {
                float4 t = base[7 * L + k];
                g[4*k] = t.x; g[4*k+1] = t.y; g[4*k+2] = t.z; g[4*k+3] = t.w;
            }
#pragma unroll
            for (int rr = 0; rr < 4; ++rr) {
                float z[7], m = -1e30f;
#pragma unroll
                for (int c = 0; c < 7; ++c) {
                    z[c] = g[7*rr+c] * cst.invT[c];
                    m = fmaxf(m, z[c]);
                }
                float S = 0.0f, dot = 0.0f;
#pragma unroll
                for (int c = 0; c < 7; ++c) {
                    S   += __expf(z[c] - m);
                    dot += q4[7*rr+c] * z[c];
                }
                cost_sum += qlogq[rr] - dot + m + __logf(S);
            }
        }
    }

    cost_sum *= (1.0f / 7.0f);   // mean over C

    // Single-wave block: shuffle-reduce, one atomic. No barriers anywhere.
#pragma unroll
    for (int off = 32; off > 0; off >>= 1)
        cost_sum += __shfl_down(cost_sum, off, 64);
    if (L == 0)
        atomicAdd(out, cost_sum * cst.scale);
}

extern "C" void kernel_launch(void* const* d_in, const int* in_sizes, int n_in,
                              void* d_out, int out_size, void* d_ws, size_t ws_size,
                              hipStream_t stream)
{
    const float* x1 = (const float*)d_in[0];
    const float* x2 = (const float*)d_in[1];
    const float* x3 = (const float*)d_in[2];
    const float* x4 = (const float*)d_in[3];
    // d_in[4] = targets: dead input, never read.

    const int N = in_sizes[0] / 7;   // 2097152

    RideConsts cst;
    {
        const double cls[7] = {705, 717, 281, 4772, 1982, 1290, 2524};
        double sum = 0.0;
        for (int c = 0; c < 7; ++c) sum += cls[c];
        double w[7], wmax = 0.0;
        for (int c = 0; c < 7; ++c) {
            const double p = cls[c] / sum;
            w[c] = 7.0 * p * 0.015 + 1.0 - 0.015;
            if (w[c] > wmax) wmax = w[c];
        }
        double mT2 = 0.0;
        for (int c = 0; c < 7; ++c) {
            const float T = (float)(1.5 * (w[c] / wmax));
            cst.invT[c] = 1.0f / T;
            mT2 += (double)T * (double)T;
        }
        mT2 /= 7.0;
        cst.scale = (float)(mT2 / (3.0 * (double)N));
    }

    hipMemsetAsync(d_out, 0, sizeof(float), stream);

    // N = 2097152 rows: 1024 single-wave blocks x 8 stages x 256 rows.
    const int grid   = 1024;
    const int stages = N / (grid * 256);   // 8, exact for this problem

    ride_kernel<<<grid, 64, 0, stream>>>(x1, x2, x3, x4, (float*)d_out,
                                         cst, stages);
}

// Round 4
// 256.861 us; speedup vs baseline: 1.0844x; 1.0844x over previous
//
#include <hip/hip_runtime.h>

// RIDE 4-way self-distillation KL loss, N x C (C=7), fp32. Scalar output.
//
// R3 post-mortem: WRITE_SIZE=229MB = scratch spills (v[28] float4 > VGPR
// budget), 2.7M LDS bank conflicts (b128 reads at word-stride 28 = 8-way),
// 10% occupancy. R1/R2/R3 cross-round model: cost scales with cache-LINE
// requests per VMEM instruction (R1's stride-112 dwordx4 = 56 lines/instr
// ~ 1.2 cyc/line = its 100 us) and LDS-DMA is ~15 cyc/line (R2).
//
// This version: classic cooperative staging with PLAIN coalesced loads.
// Block = 256 thr (4 waves). Wave w stages array w's 256-row chunk as
// 7 lane-contiguous dwordx4 (16 lines/instr) into 28 data VGPRs, commits
// via ds_write_b128 (2 lanes/bank: free). Single 28KB LDS buffer ->
// 5 blocks/CU (20 waves). Next chunk's loads issue before compute and fly
// across barriers (plain register loads don't drain vmcnt at s_barrier,
// unlike LDS-DMA). Compute: thread t owns row t; scalar LDS reads at
// word-stride 7 (gcd(7,32)=1 -> 2 lanes/bank, conflict-free).

struct RideConsts {
    float invT[7];
    float scale;   // mean(T^2) / (3*N)
};

__global__ __launch_bounds__(256) void ride_kernel(
    const float* __restrict__ x1, const float* __restrict__ x2,
    const float* __restrict__ x3, const float* __restrict__ x4,
    float* __restrict__ out, RideConsts cst, int chunksPerBlock)
{
    // [array][256 rows * 7 floats] = 4*1792*4 B = 28672 B (5 blocks/CU)
    __shared__ __align__(16) float lds[4][1792];
    __shared__ float red[4];

    const int t = threadIdx.x;
    const int w = t >> 6;     // wave id: which array this wave stages
    const int L = t & 63;

    const float* xw = (w == 0) ? x1 : (w == 1) ? x2 : (w == 2) ? x3 : x4;

    // Block b owns chunks [b*CPB, (b+1)*CPB); chunk = 256 rows = 448 float4.
    const long long c0 = (long long)blockIdx.x * chunksPerBlock;

    float4 v[7];   // staged chunk for array w: lane L holds float4 (k*64+L)

    // Prologue: load chunk 0.
    {
        const float4* gp = (const float4*)xw + c0 * 448 + L;
#pragma unroll
        for (int k = 0; k < 7; ++k) v[k] = gp[k * 64];
    }

    float cost_sum = 0.0f;

    for (int s = 0; s < chunksPerBlock; ++s) {
        __syncthreads();   // all reads of previous chunk complete

        // Commit staged chunk s to LDS (vmcnt waits resolve here; these
        // loads have been in flight for a full compute phase).
        {
            float4* dst = (float4*)&lds[w][0];
#pragma unroll
            for (int k = 0; k < 7; ++k) dst[k * 64 + L] = v[k];
        }
        __syncthreads();   // chunk s visible to all waves

        // Issue chunk s+1 loads now; they fly during the compute below and
        // across the next iteration's barriers.
        if (s + 1 < chunksPerBlock) {
            const float4* gp = (const float4*)xw + (c0 + s + 1) * 448 + L;
#pragma unroll
            for (int k = 0; k < 7; ++k) v[k] = gp[k * 64];
        }

        // ---- compute: thread t owns row t of this chunk ----
        float z0[7], q[7];
        float m = -1e30f;
#pragma unroll
        for (int c = 0; c < 7; ++c) {
            z0[c] = lds[0][7 * t + c] * cst.invT[c];
            m = fmaxf(m, z0[c]);
        }
        float S = 0.0f;
#pragma unroll
        for (int c = 0; c < 7; ++c) {
            float e = __expf(z0[c] - m);
            q[c] = e; S += e;
        }
        const float invS = 1.0f / S, logS = __logf(S);
        float qlogq = 0.0f;
#pragma unroll
        for (int c = 0; c < 7; ++c) {
            q[c] *= invS;
            qlogq += q[c] * (z0[c] - m - logS);
        }
#pragma unroll
        for (int a = 1; a < 4; ++a) {
            float z[7], mm = -1e30f;
#pragma unroll
            for (int c = 0; c < 7; ++c) {
                z[c] = lds[a][7 * t + c] * cst.invT[c];
                mm = fmaxf(mm, z[c]);
            }
            float SS = 0.0f, dot = 0.0f;
#pragma unroll
            for (int c = 0; c < 7; ++c) {
                SS  += __expf(z[c] - mm);
                dot += q[c] * z[c];
            }
            cost_sum += qlogq - dot + mm + __logf(SS);
        }
    }

    cost_sum *= (1.0f / 7.0f);   // mean over C

    // wave(64) shuffle reduction -> per-block -> one atomic
#pragma unroll
    for (int off = 32; off > 0; off >>= 1)
        cost_sum += __shfl_down(cost_sum, off, 64);
    if (L == 0) red[w] = cost_sum;
    __syncthreads();
    if (t == 0)
        atomicAdd(out, (red[0] + red[1] + red[2] + red[3]) * cst.scale);
}

extern "C" void kernel_launch(void* const* d_in, const int* in_sizes, int n_in,
                              void* d_out, int out_size, void* d_ws, size_t ws_size,
                              hipStream_t stream)
{
    const float* x1 = (const float*)d_in[0];
    const float* x2 = (const float*)d_in[1];
    const float* x3 = (const float*)d_in[2];
    const float* x4 = (const float*)d_in[3];
    // d_in[4] = targets: dead input, never read.

    const int N = in_sizes[0] / 7;   // 2097152

    RideConsts cst;
    {
        const double cls[7] = {705, 717, 281, 4772, 1982, 1290, 2524};
        double sum = 0.0;
        for (int c = 0; c < 7; ++c) sum += cls[c];
        double w[7], wmax = 0.0;
        for (int c = 0; c < 7; ++c) {
            const double p = cls[c] / sum;
            w[c] = 7.0 * p * 0.015 + 1.0 - 0.015;
            if (w[c] > wmax) wmax = w[c];
        }
        double mT2 = 0.0;
        for (int c = 0; c < 7; ++c) {
            const float T = (float)(1.5 * (w[c] / wmax));
            cst.invT[c] = 1.0f / T;
            mT2 += (double)T * (double)T;
        }
        mT2 /= 7.0;
        cst.scale = (float)(mT2 / (3.0 * (double)N));
    }

    hipMemsetAsync(d_out, 0, sizeof(float), stream);

    // 8192 chunks of 256 rows; grid 2048 -> 4 chunks/block, 8 blocks/CU
    // queued against 5-resident LDS capacity.
    const int grid           = 2048;
    const int chunksPerBlock = (N / 256) / grid;   // 4, exact

    ride_kernel<<<grid, 256, 0, stream>>>(x1, x2, x3, x4, (float*)d_out,
                                          cst, chunksPerBlock);
}

// Round 5
// 227.816 us; speedup vs baseline: 1.2226x; 1.1275x over previous
//
#include <hip/hip_runtime.h>

// RIDE 4-way self-distillation KL loss, N x C (C=7), fp32. Scalar output.
//
// R4 post-mortem: structure right, but WRITE_SIZE=218MB on a 4-byte-output
// kernel = the float4 v[7] staging array spilled to scratch (VGPR_Count=44
// can't hold it; live across a runtime-count loop iteration with conditional
// redefinition). Scratch round-trip ~doubled traffic and re-exposed load
// latency at the ds_write. Fix: compile-time CPB, fully unrolled chunk loop,
// seven NAMED float4 registers (pure SSA, no demotable array).
//
// Structure (from R4): block = 256 thr (4 waves). Wave w stages array w's
// 256-row chunk as 7 lane-contiguous dwordx4 (16 cache lines/instr) into
// registers, commits via ds_write_b128 (conflict-free, measured 0), single
// 28KB LDS buffer -> 5 blocks/CU (20 waves). Prefetch for chunk s+1 issues
// between commit and the 2nd barrier and stays in flight through compute.
// Compute: thread t owns row t; scalar LDS reads word-stride 7 (2 lanes/bank,
// free). Per-CU budget: VMEM-lines 2.7k cyc, VALU 2.4k cyc/SIMD vs HBM floor
// 5.6k cyc per 143KB round -> HBM-bound, ~38-45 us expected.

struct RideConsts {
    float invT[7];
    float scale;   // mean(T^2) / (3*N)
};

template <int CPB>
__global__ __launch_bounds__(256) void ride_kernel(
    const float* __restrict__ x1, const float* __restrict__ x2,
    const float* __restrict__ x3, const float* __restrict__ x4,
    float* __restrict__ out, RideConsts cst)
{
    // [array][256 rows * 7 floats] = 4*1792*4 B = 28672 B (5 blocks/CU)
    __shared__ __align__(16) float lds[4][1792];
    __shared__ float red[4];

    const int t = threadIdx.x;
    const int w = t >> 6;     // wave id: which array this wave stages
    const int L = t & 63;

    const float* xw = (w == 0) ? x1 : (w == 1) ? x2 : (w == 2) ? x3 : x4;

    // Block b owns chunks [b*CPB, (b+1)*CPB); chunk = 256 rows = 448 float4.
    const float4* gp0 = (const float4*)xw + (long long)blockIdx.x * CPB * 448 + L;

    // Named registers: no array, no scratch demotion.
    float4 v0, v1, v2, v3, v4, v5, v6;

    // Prologue: load chunk 0 (lane-contiguous: instr k covers 16 lines).
    v0 = gp0[0 * 64]; v1 = gp0[1 * 64]; v2 = gp0[2 * 64]; v3 = gp0[3 * 64];
    v4 = gp0[4 * 64]; v5 = gp0[5 * 64]; v6 = gp0[6 * 64];

    float cost_sum = 0.0f;

#pragma unroll
    for (int s = 0; s < CPB; ++s) {
        __syncthreads();   // all lanes done reading previous chunk's LDS

        // Commit staged chunk s (vmcnt waits for this wave's own loads,
        // issued a full compute phase ago).
        {
            float4* dst = (float4*)&lds[w][0];
            dst[0 * 64 + L] = v0; dst[1 * 64 + L] = v1; dst[2 * 64 + L] = v2;
            dst[3 * 64 + L] = v3; dst[4 * 64 + L] = v4; dst[5 * 64 + L] = v5;
            dst[6 * 64 + L] = v6;
        }

        // Issue chunk s+1 loads now (static condition: unrolled away on the
        // last iteration). They fly across the barrier and the compute.
        if (s + 1 < CPB) {
            const float4* gp = gp0 + (s + 1) * 448;
            v0 = gp[0 * 64]; v1 = gp[1 * 64]; v2 = gp[2 * 64];
            v3 = gp[3 * 64]; v4 = gp[4 * 64]; v5 = gp[5 * 64];
            v6 = gp[6 * 64];
        }

        __syncthreads();   // chunk s visible to all waves

        // ---- compute: thread t owns row t of this chunk ----
        float z0[7], q[7];
        float m = -1e30f;
#pragma unroll
        for (int c = 0; c < 7; ++c) {
            z0[c] = lds[0][7 * t + c] * cst.invT[c];
            m = fmaxf(m, z0[c]);
        }
        float S = 0.0f;
#pragma unroll
        for (int c = 0; c < 7; ++c) {
            float e = __expf(z0[c] - m);
            q[c] = e; S += e;
        }
        const float invS = 1.0f / S, logS = __logf(S);
        float qlogq = 0.0f;
#pragma unroll
        for (int c = 0; c < 7; ++c) {
            q[c] *= invS;
            qlogq += q[c] * (z0[c] - m - logS);
        }
#pragma unroll
        for (int a = 1; a < 4; ++a) {
            float z[7], mm = -1e30f;
#pragma unroll
            for (int c = 0; c < 7; ++c) {
                z[c] = lds[a][7 * t + c] * cst.invT[c];
                mm = fmaxf(mm, z[c]);
            }
            float SS = 0.0f, dot = 0.0f;
#pragma unroll
            for (int c = 0; c < 7; ++c) {
                SS  += __expf(z[c] - mm);
                dot += q[c] * z[c];
            }
            cost_sum += qlogq - dot + mm + __logf(SS);
        }
    }

    cost_sum *= (1.0f / 7.0f);   // mean over C

    // wave(64) shuffle reduction -> per-block -> one atomic
#pragma unroll
    for (int off = 32; off > 0; off >>= 1)
        cost_sum += __shfl_down(cost_sum, off, 64);
    if (L == 0) red[w] = cost_sum;
    __syncthreads();
    if (t == 0)
        atomicAdd(out, (red[0] + red[1] + red[2] + red[3]) * cst.scale);
}

extern "C" void kernel_launch(void* const* d_in, const int* in_sizes, int n_in,
                              void* d_out, int out_size, void* d_ws, size_t ws_size,
                              hipStream_t stream)
{
    const float* x1 = (const float*)d_in[0];
    const float* x2 = (const float*)d_in[1];
    const float* x3 = (const float*)d_in[2];
    const float* x4 = (const float*)d_in[3];
    // d_in[4] = targets: dead input, never read.

    const int N = in_sizes[0] / 7;   // 2097152

    RideConsts cst;
    {
        const double cls[7] = {705, 717, 281, 4772, 1982, 1290, 2524};
        double sum = 0.0;
        for (int c = 0; c < 7; ++c) sum += cls[c];
        double w[7], wmax = 0.0;
        for (int c = 0; c < 7; ++c) {
            const double p = cls[c] / sum;
            w[c] = 7.0 * p * 0.015 + 1.0 - 0.015;
            if (w[c] > wmax) wmax = w[c];
        }
        double mT2 = 0.0;
        for (int c = 0; c < 7; ++c) {
            const float T = (float)(1.5 * (w[c] / wmax));
            cst.invT[c] = 1.0f / T;
            mT2 += (double)T * (double)T;
        }
        mT2 /= 7.0;
        cst.scale = (float)(mT2 / (3.0 * (double)N));
    }

    hipMemsetAsync(d_out, 0, sizeof(float), stream);

    // N = 2097152 rows = 8192 chunks of 256 rows; CPB=4 -> grid 2048 (exact).
    constexpr int CPB = 4;
    const int grid = (N / 256) / CPB;   // 2048

    ride_kernel<CPB><<<grid, 256, 0, stream>>>(x1, x2, x3, x4, (float*)d_out,
                                               cst);
}

// Round 6
// 226.502 us; speedup vs baseline: 1.2297x; 1.0058x over previous
//
#include <hip/hip_runtime.h>

// RIDE 4-way self-distillation KL loss, N x C (C=7), fp32. Scalar output.
//
// R5 post-mortem: VGPR_Count=44 proves the compiler sank the "prefetch"
// loads to the ds_write (can't hold 28 staged VGPRs) -> every iteration is
// barrier -> load -> full-latency wait -> commit -> barrier -> compute, a
// whole-block convoy. And L3-resident replays (hbm_bytes=65KB) ran the same
// 88 us as HBM-hot ones: the ~2.6 TB/s floor is on-chip serialization
// (barrier drains + convoy + 2048-way same-address atomic tail), not BW.
//
// R6: delete all synchronization from the hot path.
//  - Wave-private single-buffer LDS (7168 B/wave), ZERO __syncthreads.
//    Per array-step: ds_write staged regs -> issue next step's 7 loads ->
//    compute from own LDS. Same-wave LDS ordering makes the single buffer
//    correct; stalls are per-wave; 20 independent waves/CU (5 blocks x
//    28.7KB) cover them.
//  - Row->lane map keeps R5's conflict-free stride-7-word b32 ds_reads
//    (lane L computes rows L,L+64,L+128,L+192) and blocks b128-merging
//    (which would be 8-way-conflicted at stride 28).
//  - No atomics: per-wave partials -> d_ws, second tiny kernel reduces.
//  - __launch_bounds__(256,5): VGPR cap 102, keeps q[28]+staging resident.

struct RideConsts {
    float invT[7];
    float scale;   // mean(T^2) / (3*N)
};

template <int CPW>   // chunks (256 rows) per wave
__global__ __launch_bounds__(256, 5) void ride_main(
    const float* __restrict__ x1, const float* __restrict__ x2,
    const float* __restrict__ x3, const float* __restrict__ x4,
    float* __restrict__ partials, RideConsts cst)
{
    // 4 waves/block, each with a private 1792-float region. 28672 B total.
    __shared__ __align__(16) float lds[4][1792];

    const int t = threadIdx.x;
    const int w = t >> 6;
    const int L = t & 63;
    float* myLds = lds[w];

    const float* xs[4] = {x1, x2, x3, x4};
    const int waveId = blockIdx.x * 4 + w;

    // float4 base for (chunk c, array a): (f4*)xs[a] + (waveId*CPW + c)*448 + L
    const long long cbase = (long long)waveId * CPW * 448 + L;

    float4 v0, v1, v2, v3, v4, v5, v6;

    // Prologue: load step 0 (chunk 0, array 0). Lane-contiguous dwordx4.
    {
        const float4* gp = (const float4*)xs[0] + cbase;
        v0 = gp[0];   v1 = gp[64];  v2 = gp[128]; v3 = gp[192];
        v4 = gp[256]; v5 = gp[320]; v6 = gp[384];
    }

    float q[28], qlogq[4];
    float cost = 0.0f;

#pragma unroll
    for (int c = 0; c < CPW; ++c) {
#pragma unroll
        for (int a = 0; a < 4; ++a) {
            // 1) Commit staged step to private LDS (vmcnt for loads issued
            //    one full compute-step ago). ds_write_b128, conflict-free.
            {
                float4* dst = (float4*)myLds;
                dst[0 * 64 + L] = v0; dst[1 * 64 + L] = v1;
                dst[2 * 64 + L] = v2; dst[3 * 64 + L] = v3;
                dst[4 * 64 + L] = v4; dst[5 * 64 + L] = v5;
                dst[6 * 64 + L] = v6;
            }

            // 2) Issue next step's loads (static condition; none on the very
            //    last step). They fly during the compute below. No barrier
            //    ever drains them.
            if (c * 4 + a + 1 < CPW * 4) {
                const int na = (a + 1) & 3;
                const int nc = (a == 3) ? c + 1 : c;
                const float4* gp = (const float4*)xs[na] + (cbase + nc * 448);
                v0 = gp[0];   v1 = gp[64];  v2 = gp[128]; v3 = gp[192];
                v4 = gp[256]; v5 = gp[320]; v6 = gp[384];
            }

            // 3) Compute this step: lane L owns rows L+64*rr, at word offset
            //    7L + 448*rr (stride-7 b32 reads: 2 lanes/bank, free).
            if (a == 0) {
#pragma unroll
                for (int rr = 0; rr < 4; ++rr) {
                    const float* r = &myLds[7 * L + 448 * rr];
                    float z[7], m = -1e30f;
#pragma unroll
                    for (int cc = 0; cc < 7; ++cc) {
                        z[cc] = r[cc] * cst.invT[cc];
                        m = fmaxf(m, z[cc]);
                    }
                    float S = 0.0f;
#pragma unroll
                    for (int cc = 0; cc < 7; ++cc) {
                        float e = __expf(z[cc] - m);
                        q[7 * rr + cc] = e; S += e;
                    }
                    const float invS = 1.0f / S, logS = __logf(S);
                    float sq = 0.0f;
#pragma unroll
                    for (int cc = 0; cc < 7; ++cc) {
                        float qq = q[7 * rr + cc] * invS;
                        q[7 * rr + cc] = qq;
                        sq += qq * (z[cc] - m - logS);
                    }
                    qlogq[rr] = sq;
                }
            } else {
#pragma unroll
                for (int rr = 0; rr < 4; ++rr) {
                    const float* r = &myLds[7 * L + 448 * rr];
                    float z[7], m = -1e30f;
#pragma unroll
                    for (int cc = 0; cc < 7; ++cc) {
                        z[cc] = r[cc] * cst.invT[cc];
                        m = fmaxf(m, z[cc]);
                    }
                    float S = 0.0f, dot = 0.0f;
#pragma unroll
                    for (int cc = 0; cc < 7; ++cc) {
                        S   += __expf(z[cc] - m);
                        dot += q[7 * rr + cc] * z[cc];
                    }
                    cost += qlogq[rr] - dot + m + __logf(S);
                }
            }
        }
    }

    cost *= (1.0f / 7.0f);   // mean over C
    cost *= cst.scale;

    // Wave-level reduce; one plain store per wave. No atomics, no barriers.
#pragma unroll
    for (int off = 32; off > 0; off >>= 1)
        cost += __shfl_down(cost, off, 64);
    if (L == 0) partials[waveId] = cost;
}

__global__ __launch_bounds__(256) void ride_reduce(
    const float* __restrict__ p, float* __restrict__ out, int n)
{
    float s = 0.0f;
    for (int i = threadIdx.x; i < n; i += 256) s += p[i];
#pragma unroll
    for (int off = 32; off > 0; off >>= 1)
        s += __shfl_down(s, off, 64);
    __shared__ float red[4];
    if ((threadIdx.x & 63) == 0) red[threadIdx.x >> 6] = s;
    __syncthreads();
    if (threadIdx.x == 0) out[0] = red[0] + red[1] + red[2] + red[3];
}

extern "C" void kernel_launch(void* const* d_in, const int* in_sizes, int n_in,
                              void* d_out, int out_size, void* d_ws, size_t ws_size,
                              hipStream_t stream)
{
    const float* x1 = (const float*)d_in[0];
    const float* x2 = (const float*)d_in[1];
    const float* x3 = (const float*)d_in[2];
    const float* x4 = (const float*)d_in[3];
    // d_in[4] = targets: dead input, never read.

    const int N = in_sizes[0] / 7;   // 2097152

    RideConsts cst;
    {
        const double cls[7] = {705, 717, 281, 4772, 1982, 1290, 2524};
        double sum = 0.0;
        for (int c = 0; c < 7; ++c) sum += cls[c];
        double w[7], wmax = 0.0;
        for (int c = 0; c < 7; ++c) {
            const double p = cls[c] / sum;
            w[c] = 7.0 * p * 0.015 + 1.0 - 0.015;
            if (w[c] > wmax) wmax = w[c];
        }
        double mT2 = 0.0;
        for (int c = 0; c < 7; ++c) {
            const float T = (float)(1.5 * (w[c] / wmax));
            cst.invT[c] = 1.0f / T;
            mT2 += (double)T * (double)T;
        }
        mT2 /= 7.0;
        cst.scale = (float)(mT2 / (3.0 * (double)N));
    }

    // N = 2097152 rows = 8192 chunks of 256 rows.
    // 512 blocks x 4 waves = 2048 waves x CPW=4 chunks (exact).
    constexpr int CPW = 4;
    const int nWaves = (N / 256) / CPW;     // 2048
    const int grid   = nWaves / 4;          // 512

    float* partials = (float*)d_ws;         // 2048 floats = 8 KB scratch

    ride_main<CPW><<<grid, 256, 0, stream>>>(x1, x2, x3, x4, partials, cst);
    ride_reduce<<<1, 256, 0, stream>>>(partials, (float*)d_out, nWaves);
}